// Round 1
// baseline (4457.814 us; speedup 1.0000x reference)
//
#include <hip/hip_runtime.h>
#include <math.h>

#define NND 200000
#define NEV 100000
#define MD 100
#define TD 100
#define MSGD 172
#define NB 64
#define LST 65  // LDS node stride (64 + 1 pad)

__device__ __forceinline__ float sigmoidf_(float x) { return 1.0f / (1.0f + expf(-x)); }

// ---------------- scatter: per-event message accumulation ----------------
__global__ __launch_bounds__(256) void tgn_scatter(
    const float* __restrict__ memory, const float* __restrict__ raw_msg,
    const float* __restrict__ time_w, const float* __restrict__ time_b,
    const int* __restrict__ last_update, const int* __restrict__ src,
    const int* __restrict__ dst, const int* __restrict__ tarr,
    float* __restrict__ counts, float* __restrict__ S2,
    float* __restrict__ S3, float* __restrict__ S4)
{
    int e = blockIdx.x * 4 + (threadIdx.x >> 6);
    if (e >= NEV) return;
    int lane = threadIdx.x & 63;
    int s = src[e], d = dst[e];
    int tt = tarr[e];
    float trs = (float)(tt - last_update[s]);
    float trd = (float)(tt - last_update[d]);

    for (int k = lane; k < MSGD; k += 64) {
        float r = raw_msg[e * MSGD + k];
        unsafeAtomicAdd(&S3[(size_t)s * MSGD + k], r);
        unsafeAtomicAdd(&S3[(size_t)d * MSGD + k], r);
    }
    for (int k = lane; k < MD; k += 64) {
        float ms = memory[(size_t)s * MD + k];
        float md = memory[(size_t)d * MD + k];
        unsafeAtomicAdd(&S2[(size_t)s * MD + k], md);
        unsafeAtomicAdd(&S2[(size_t)d * MD + k], ms);
        float tw = time_w[k];
        float tb = time_b[k];
        unsafeAtomicAdd(&S4[(size_t)s * TD + k], cosf(trs * tw + tb));
        unsafeAtomicAdd(&S4[(size_t)d * TD + k], cosf(trd * tw + tb));
    }
    if (lane == 0) {
        unsafeAtomicAdd(&counts[s], 1.0f);
        unsafeAtomicAdd(&counts[d], 1.0f);
    }
}

// ---------------- GRU GEMV over a 64-node tile ----------------
// ag layout: ag[k*LST + n], k in [0,472): [mem(100) | S2/c(100) | S3/c(172) | S4/c(100)]
template<int D>
__device__ __forceinline__ void gru_chunk(
    const float* ag, float cflag, int n, int j0,
    const float4* __restrict__ wi4, const float4* __restrict__ wh4,
    const float* __restrict__ b_ih, const float* __restrict__ b_hh,
    int gbase, float* __restrict__ out)
{
    float aR[D], aZ[D], aN[D], hR[D], hZ[D], hN[D];
#pragma unroll
    for (int m = 0; m < D; ++m) {
        aR[m] = b_ih[j0 + m];
        aZ[m] = b_ih[100 + j0 + m];
        aN[m] = b_ih[200 + j0 + m];
        hR[m] = b_hh[j0 + m];
        hZ[m] = b_hh[100 + j0 + m];
        hN[m] = b_hh[200 + j0 + m];
    }
    // k in [0,100): feeds gi (aggr mem part) and gh (memory)
    for (int k4 = 0; k4 < 25; ++k4) {
        float vx = ag[(4 * k4 + 0) * LST + n];
        float vy = ag[(4 * k4 + 1) * LST + n];
        float vz = ag[(4 * k4 + 2) * LST + n];
        float vw = ag[(4 * k4 + 3) * LST + n];
#pragma unroll
        for (int m = 0; m < D; ++m) {
            float4 w0 = wi4[(j0 + m) * 118 + k4];
            aR[m] = fmaf(vx, w0.x, fmaf(vy, w0.y, fmaf(vz, w0.z, fmaf(vw, w0.w, aR[m]))));
            float4 w1 = wi4[(100 + j0 + m) * 118 + k4];
            aZ[m] = fmaf(vx, w1.x, fmaf(vy, w1.y, fmaf(vz, w1.z, fmaf(vw, w1.w, aZ[m]))));
            float4 w2 = wi4[(200 + j0 + m) * 118 + k4];
            aN[m] = fmaf(vx, w2.x, fmaf(vy, w2.y, fmaf(vz, w2.z, fmaf(vw, w2.w, aN[m]))));
            float4 u0 = wh4[(j0 + m) * 25 + k4];
            hR[m] = fmaf(vx, u0.x, fmaf(vy, u0.y, fmaf(vz, u0.z, fmaf(vw, u0.w, hR[m]))));
            float4 u1 = wh4[(100 + j0 + m) * 25 + k4];
            hZ[m] = fmaf(vx, u1.x, fmaf(vy, u1.y, fmaf(vz, u1.z, fmaf(vw, u1.w, hZ[m]))));
            float4 u2 = wh4[(200 + j0 + m) * 25 + k4];
            hN[m] = fmaf(vx, u2.x, fmaf(vy, u2.y, fmaf(vz, u2.z, fmaf(vw, u2.w, hN[m]))));
        }
    }
    // k in [100,472): gi only
    for (int k4 = 25; k4 < 118; ++k4) {
        float vx = ag[(4 * k4 + 0) * LST + n];
        float vy = ag[(4 * k4 + 1) * LST + n];
        float vz = ag[(4 * k4 + 2) * LST + n];
        float vw = ag[(4 * k4 + 3) * LST + n];
#pragma unroll
        for (int m = 0; m < D; ++m) {
            float4 w0 = wi4[(j0 + m) * 118 + k4];
            aR[m] = fmaf(vx, w0.x, fmaf(vy, w0.y, fmaf(vz, w0.z, fmaf(vw, w0.w, aR[m]))));
            float4 w1 = wi4[(100 + j0 + m) * 118 + k4];
            aZ[m] = fmaf(vx, w1.x, fmaf(vy, w1.y, fmaf(vz, w1.z, fmaf(vw, w1.w, aZ[m]))));
            float4 w2 = wi4[(200 + j0 + m) * 118 + k4];
            aN[m] = fmaf(vx, w2.x, fmaf(vy, w2.y, fmaf(vz, w2.z, fmaf(vw, w2.w, aN[m]))));
        }
    }
#pragma unroll
    for (int m = 0; m < D; ++m) {
        float r = sigmoidf_(aR[m] + hR[m]);
        float z = sigmoidf_(aZ[m] + hZ[m]);
        float nn = tanhf(aN[m] + r * hN[m]);
        float mv = ag[(j0 + m) * LST + n];  // memory value (k<100 region)
        float h = (1.0f - z) * nn + z * mv;
        out[gbase + j0 + m] = (cflag > 0.0f) ? h : mv;
    }
}

__global__ __launch_bounds__(512, 2) void tgn_gru(
    const float* __restrict__ memory,
    const float* __restrict__ w_ih, const float* __restrict__ w_hh,
    const float* __restrict__ b_ih, const float* __restrict__ b_hh,
    const float* __restrict__ counts, const float* __restrict__ S2,
    const float* __restrict__ S3, const float* __restrict__ S4,
    float* __restrict__ out)
{
    __shared__ float ag[472 * LST];
    __shared__ float cnt_s[NB];
    __shared__ float cinv_s[NB];
    int tid = threadIdx.x;
    int n0 = blockIdx.x * NB;

    if (tid < NB) {
        float c = counts[n0 + tid];
        cnt_s[tid] = c;
        cinv_s[tid] = 1.0f / fmaxf(c, 1.0f);
    }
    __syncthreads();

    // stage aggr transposed: ag[k][n]
    for (int idx = tid; idx < NB * MD; idx += 512) {
        int n = idx / MD, k = idx - n * MD;
        ag[k * LST + n] = memory[(size_t)(n0 + n) * MD + k];
    }
    for (int idx = tid; idx < NB * MD; idx += 512) {
        int n = idx / MD, k = idx - n * MD;
        ag[(100 + k) * LST + n] = S2[(size_t)(n0 + n) * MD + k] * cinv_s[n];
    }
    for (int idx = tid; idx < NB * MSGD; idx += 512) {
        int n = idx / MSGD, k = idx - n * MSGD;
        ag[(200 + k) * LST + n] = S3[(size_t)(n0 + n) * MSGD + k] * cinv_s[n];
    }
    for (int idx = tid; idx < NB * TD; idx += 512) {
        int n = idx / TD, k = idx - n * TD;
        ag[(372 + k) * LST + n] = S4[(size_t)(n0 + n) * TD + k] * cinv_s[n];
    }
    __syncthreads();

    int lane = tid & 63;
    int wv = __builtin_amdgcn_readfirstlane(tid >> 6);
    // waves 0..3 -> 13 gate dims, waves 4..7 -> 12 (total 100)
    int j0 = wv * 12 + ((wv < 4) ? wv : 4);
    float cflag = cnt_s[lane];
    int gbase = (n0 + lane) * MD;
    const float4* wi4 = (const float4*)w_ih;
    const float4* wh4 = (const float4*)w_hh;

    if (wv < 4) {
        gru_chunk<7>(ag, cflag, lane, j0, wi4, wh4, b_ih, b_hh, gbase, out);
        gru_chunk<6>(ag, cflag, lane, j0 + 7, wi4, wh4, b_ih, b_hh, gbase, out);
    } else {
        gru_chunk<6>(ag, cflag, lane, j0, wi4, wh4, b_ih, b_hh, gbase, out);
        gru_chunk<6>(ag, cflag, lane, j0 + 6, wi4, wh4, b_ih, b_hh, gbase, out);
    }
}

extern "C" void kernel_launch(void* const* d_in, const int* in_sizes, int n_in,
                              void* d_out, int out_size, void* d_ws, size_t ws_size,
                              hipStream_t stream)
{
    const float* memory      = (const float*)d_in[0];
    const float* raw_msg     = (const float*)d_in[1];
    const float* time_w      = (const float*)d_in[2];
    const float* time_b      = (const float*)d_in[3];
    const float* w_ih        = (const float*)d_in[4];
    const float* w_hh        = (const float*)d_in[5];
    const float* b_ih        = (const float*)d_in[6];
    const float* b_hh        = (const float*)d_in[7];
    const int*   last_update = (const int*)d_in[8];
    const int*   src         = (const int*)d_in[9];
    const int*   dst         = (const int*)d_in[10];
    const int*   tarr        = (const int*)d_in[11];
    float* out = (float*)d_out;

    // ws layout (floats): counts[N] | S2[N*100] | S3[N*172] | S4[N*100]
    size_t need = (size_t)373 * NND * sizeof(float);
    if (ws_size < need) return;  // fail loudly (output stays poisoned)
    float* ws     = (float*)d_ws;
    float* counts = ws;
    float* S2     = ws + (size_t)NND;
    float* S3     = ws + (size_t)101 * NND;
    float* S4     = ws + (size_t)273 * NND;

    hipMemsetAsync(d_ws, 0, need, stream);
    tgn_scatter<<<NEV / 4, 256, 0, stream>>>(memory, raw_msg, time_w, time_b,
                                             last_update, src, dst, tarr,
                                             counts, S2, S3, S4);
    tgn_gru<<<NND / NB, 512, 0, stream>>>(memory, w_ih, w_hh, b_ih, b_hh,
                                          counts, S2, S3, S4, out);
}

// Round 2
// 911.302 us; speedup vs baseline: 4.8917x; 4.8917x over previous
//
#include <hip/hip_runtime.h>
#include <math.h>

#define NND 200000
#define NEV 100000
#define MD 100
#define TD 100
#define MSGD 172
#define NB 64

typedef __attribute__((ext_vector_type(8))) short bf16x8;
typedef __attribute__((ext_vector_type(4))) float f32x4;

__device__ __forceinline__ float sigmoidf_(float x) { return 1.0f / (1.0f + expf(-x)); }

__device__ __forceinline__ unsigned short f2bf(float f) {
    union { float f; unsigned int u; } v; v.f = f;
    unsigned int r = (v.u + 0x7FFFu + ((v.u >> 16) & 1u)) >> 16;
    return (unsigned short)r;
}
__device__ __forceinline__ float bf2f(unsigned short h) {
    union { unsigned int u; float f; } v; v.u = ((unsigned int)h) << 16;
    return v.f;
}

// ---------------- scatter: per-event message accumulation (unchanged) ----------------
__global__ __launch_bounds__(256) void tgn_scatter(
    const float* __restrict__ memory, const float* __restrict__ raw_msg,
    const float* __restrict__ time_w, const float* __restrict__ time_b,
    const int* __restrict__ last_update, const int* __restrict__ src,
    const int* __restrict__ dst, const int* __restrict__ tarr,
    float* __restrict__ counts, float* __restrict__ S2,
    float* __restrict__ S3, float* __restrict__ S4)
{
    int e = blockIdx.x * 4 + (threadIdx.x >> 6);
    if (e >= NEV) return;
    int lane = threadIdx.x & 63;
    int s = src[e], d = dst[e];
    int tt = tarr[e];
    float trs = (float)(tt - last_update[s]);
    float trd = (float)(tt - last_update[d]);

    for (int k = lane; k < MSGD; k += 64) {
        float r = raw_msg[e * MSGD + k];
        unsafeAtomicAdd(&S3[(size_t)s * MSGD + k], r);
        unsafeAtomicAdd(&S3[(size_t)d * MSGD + k], r);
    }
    for (int k = lane; k < MD; k += 64) {
        float ms = memory[(size_t)s * MD + k];
        float md = memory[(size_t)d * MD + k];
        unsafeAtomicAdd(&S2[(size_t)s * MD + k], md);
        unsafeAtomicAdd(&S2[(size_t)d * MD + k], ms);
        float tw = time_w[k];
        float tb = time_b[k];
        unsafeAtomicAdd(&S4[(size_t)s * TD + k], cosf(trs * tw + tb));
        unsafeAtomicAdd(&S4[(size_t)d * TD + k], cosf(trd * tw + tb));
    }
    if (lane == 0) {
        unsafeAtomicAdd(&counts[s], 1.0f);
        unsafeAtomicAdd(&counts[d], 1.0f);
    }
}

// ---------------- weight prep: bf16, transposed-padded ----------------
// Wt[col][k]: col in [0,320) (gate row, pad>=300 zero), k in [0,480) (pad>=472 zero)
// Ut[col][k]: col in [0,320), k in [0,128) (pad>=100 zero)
__global__ __launch_bounds__(256) void tgn_prep(
    const float* __restrict__ w_ih, const float* __restrict__ w_hh,
    unsigned short* __restrict__ Wt, unsigned short* __restrict__ Ut)
{
    int idx = blockIdx.x * 256 + threadIdx.x;
    if (idx < 320 * 480) {
        int col = idx / 480, k = idx - col * 480;
        float v = (col < 300 && k < 472) ? w_ih[col * 472 + k] : 0.0f;
        Wt[idx] = f2bf(v);
    } else {
        int j = idx - 320 * 480;
        if (j < 320 * 128) {
            int col = j >> 7, k = j & 127;
            float v = (col < 300 && k < 100) ? w_hh[col * 100 + k] : 0.0f;
            Ut[j] = f2bf(v);
        }
    }
}

// ---------------- GRU via bf16 MFMA over 64-node tiles ----------------
// LDS ag: bf16 [64 nodes][480 k], XOR-swizzled: byte ^= (row&7)<<4
__global__ __launch_bounds__(512) void tgn_gru(
    const float* __restrict__ memory,
    const unsigned short* __restrict__ Wt, const unsigned short* __restrict__ Ut,
    const float* __restrict__ b_ih, const float* __restrict__ b_hh,
    const float* __restrict__ counts, const float* __restrict__ S2,
    const float* __restrict__ S3, const float* __restrict__ S4,
    float* __restrict__ out)
{
    __shared__ __align__(16) unsigned short lds[64 * 480];  // 61440 B, reused by epilogue
    __shared__ float cnt_s[NB], cinv_s[NB];
    int tid = threadIdx.x;
    int n0 = blockIdx.x * NB;

    if (tid < NB) {
        float c = counts[n0 + tid];
        cnt_s[tid] = c;
        cinv_s[tid] = 1.0f / fmaxf(c, 1.0f);
    }
    __syncthreads();

    auto stage4 = [&](int n, int k, float x, float y, float z, float w) {
        int byte = (n * 960 + 2 * k) ^ ((n & 7) << 4);
        ushort4 h;
        h.x = f2bf(x); h.y = f2bf(y); h.z = f2bf(z); h.w = f2bf(w);
        *reinterpret_cast<ushort4*>(reinterpret_cast<char*>(lds) + byte) = h;
    };

    // cols [0,100): memory
    for (int i = tid; i < 1600; i += 512) {
        int n = i / 25, q = i - n * 25;
        float4 v = reinterpret_cast<const float4*>(memory)[(size_t)(n0 + n) * 25 + q];
        stage4(n, 4 * q, v.x, v.y, v.z, v.w);
    }
    // cols [100,200): S2 / counts
    for (int i = tid; i < 1600; i += 512) {
        int n = i / 25, q = i - n * 25;
        float4 v = reinterpret_cast<const float4*>(S2)[(size_t)(n0 + n) * 25 + q];
        float ci = cinv_s[n];
        stage4(n, 100 + 4 * q, v.x * ci, v.y * ci, v.z * ci, v.w * ci);
    }
    // cols [200,372): S3 / counts
    for (int i = tid; i < 2752; i += 512) {
        int n = i / 43, q = i - n * 43;
        float4 v = reinterpret_cast<const float4*>(S3)[(size_t)(n0 + n) * 43 + q];
        float ci = cinv_s[n];
        stage4(n, 200 + 4 * q, v.x * ci, v.y * ci, v.z * ci, v.w * ci);
    }
    // cols [372,472): S4 / counts
    for (int i = tid; i < 1600; i += 512) {
        int n = i / 25, q = i - n * 25;
        float4 v = reinterpret_cast<const float4*>(S4)[(size_t)(n0 + n) * 25 + q];
        float ci = cinv_s[n];
        stage4(n, 372 + 4 * q, v.x * ci, v.y * ci, v.z * ci, v.w * ci);
    }
    // cols [472,480): zero pad
    for (int i = tid; i < 128; i += 512) {
        int n = i >> 1, q = i & 1;
        stage4(n, 472 + 4 * q, 0.0f, 0.0f, 0.0f, 0.0f);
    }
    __syncthreads();

    // wave layout: 2 M-groups x 4 N-groups; wave = 2 row-frags x 5 col-frags
    int lane = tid & 63;
    int wv = tid >> 6;
    int nw = wv & 3;   // N group: cols [nw*80, +80)
    int mw = wv >> 2;  // M group: rows [mw*32, +32)
    int l15 = lane & 15;
    int kg = (lane >> 4) << 3;  // 0,8,16,24

    f32x4 accA[2][5], accH[2][5];
#pragma unroll
    for (int g = 0; g < 2; ++g)
#pragma unroll
        for (int f = 0; f < 5; ++f) {
            accA[g][f] = (f32x4){0.f, 0.f, 0.f, 0.f};
            accH[g][f] = (f32x4){0.f, 0.f, 0.f, 0.f};
        }

    int arow0 = mw * 32 + l15;
    const unsigned short* Wl = Wt + (size_t)(nw * 80 + l15) * 480 + kg;
    const unsigned short* Ul = Ut + (size_t)(nw * 80 + l15) * 128 + kg;

    // gi: K = 480 (15 steps)
    for (int ks = 0; ks < 15; ++ks) {
        int k0 = ks * 32;
        bf16x8 a0, a1;
        {
            int r0 = arow0, r1 = arow0 + 16;
            int ab0 = (r0 * 960 + 2 * (k0 + kg)) ^ ((r0 & 7) << 4);
            int ab1 = (r1 * 960 + 2 * (k0 + kg)) ^ ((r1 & 7) << 4);
            a0 = *reinterpret_cast<const bf16x8*>(reinterpret_cast<const char*>(lds) + ab0);
            a1 = *reinterpret_cast<const bf16x8*>(reinterpret_cast<const char*>(lds) + ab1);
        }
        const unsigned short* wp = Wl + k0;
#pragma unroll
        for (int f = 0; f < 5; ++f) {
            bf16x8 b = *reinterpret_cast<const bf16x8*>(wp + f * (16 * 480));
            accA[0][f] = __builtin_amdgcn_mfma_f32_16x16x32_bf16(a0, b, accA[0][f], 0, 0, 0);
            accA[1][f] = __builtin_amdgcn_mfma_f32_16x16x32_bf16(a1, b, accA[1][f], 0, 0, 0);
        }
    }
    // gh: K = 128 (4 steps); ag cols 100..127 are garbage but Ut is zero there
    for (int ks = 0; ks < 4; ++ks) {
        int k0 = ks * 32;
        bf16x8 a0, a1;
        {
            int r0 = arow0, r1 = arow0 + 16;
            int ab0 = (r0 * 960 + 2 * (k0 + kg)) ^ ((r0 & 7) << 4);
            int ab1 = (r1 * 960 + 2 * (k0 + kg)) ^ ((r1 & 7) << 4);
            a0 = *reinterpret_cast<const bf16x8*>(reinterpret_cast<const char*>(lds) + ab0);
            a1 = *reinterpret_cast<const bf16x8*>(reinterpret_cast<const char*>(lds) + ab1);
        }
        const unsigned short* up = Ul + k0;
#pragma unroll
        for (int f = 0; f < 5; ++f) {
            bf16x8 b = *reinterpret_cast<const bf16x8*>(up + f * (16 * 128));
            accH[0][f] = __builtin_amdgcn_mfma_f32_16x16x32_bf16(a0, b, accH[0][f], 0, 0, 0);
            accH[1][f] = __builtin_amdgcn_mfma_f32_16x16x32_bf16(a1, b, accH[1][f], 0, 0, 0);
        }
    }

    __syncthreads();  // all waves done reading ag; reuse LDS for gate staging

    // LDS reuse: gsum bf16 [64][208] | gin bf16 [64][104] | ghn bf16 [64][104]
    unsigned short* gsum = lds;
    unsigned short* gin = lds + 64 * 208;
    unsigned short* ghn = gin + 64 * 104;

#pragma unroll
    for (int f = 0; f < 5; ++f) {
        int col = nw * 80 + f * 16 + l15;
        if (col < 300) {
            float bi = b_ih[col], bh = b_hh[col];
#pragma unroll
            for (int g = 0; g < 2; ++g) {
                int node0 = mw * 32 + g * 16 + ((lane >> 4) << 2);
#pragma unroll
                for (int r = 0; r < 4; ++r) {
                    int node = node0 + r;
                    float gi = accA[g][f][r] + bi;
                    float gh = accH[g][f][r] + bh;
                    if (col < 200) {
                        gsum[node * 208 + col] = f2bf(gi + gh);
                    } else {
                        gin[node * 104 + (col - 200)] = f2bf(gi);
                        ghn[node * 104 + (col - 200)] = f2bf(gh);
                    }
                }
            }
        }
    }
    __syncthreads();

    // recombine gates -> GRU output
    for (int idx = tid; idx < NB * MD; idx += 512) {
        int n = idx / MD, j = idx - n * MD;
        float rp = bf2f(gsum[n * 208 + j]);
        float zp = bf2f(gsum[n * 208 + 100 + j]);
        float inv = bf2f(gin[n * 104 + j]);
        float hnv = bf2f(ghn[n * 104 + j]);
        float r = sigmoidf_(rp);
        float z = sigmoidf_(zp);
        float nn = tanhf(inv + r * hnv);
        float mv = memory[(size_t)(n0 + n) * MD + j];
        float h = (1.0f - z) * nn + z * mv;
        out[(size_t)(n0 + n) * MD + j] = (cnt_s[n] > 0.0f) ? h : mv;
    }
}

extern "C" void kernel_launch(void* const* d_in, const int* in_sizes, int n_in,
                              void* d_out, int out_size, void* d_ws, size_t ws_size,
                              hipStream_t stream)
{
    const float* memory      = (const float*)d_in[0];
    const float* raw_msg     = (const float*)d_in[1];
    const float* time_w      = (const float*)d_in[2];
    const float* time_b      = (const float*)d_in[3];
    const float* w_ih        = (const float*)d_in[4];
    const float* w_hh        = (const float*)d_in[5];
    const float* b_ih        = (const float*)d_in[6];
    const float* b_hh        = (const float*)d_in[7];
    const int*   last_update = (const int*)d_in[8];
    const int*   src         = (const int*)d_in[9];
    const int*   dst         = (const int*)d_in[10];
    const int*   tarr        = (const int*)d_in[11];
    float* out = (float*)d_out;

    // ws layout (floats): counts[N] | S2[N*100] | S3[N*172] | S4[N*100] | Wt | Ut
    size_t s_floats = (size_t)373 * NND;
    size_t need = s_floats * sizeof(float) + (320 * 480 + 320 * 128) * sizeof(unsigned short);
    if (ws_size < need) return;
    float* ws     = (float*)d_ws;
    float* counts = ws;
    float* S2     = ws + (size_t)NND;
    float* S3     = ws + (size_t)101 * NND;
    float* S4     = ws + (size_t)273 * NND;
    unsigned short* Wt = (unsigned short*)(ws + s_floats);
    unsigned short* Ut = Wt + 320 * 480;

    hipMemsetAsync(d_ws, 0, s_floats * sizeof(float), stream);
    tgn_prep<<<(320 * 480 + 320 * 128 + 255) / 256, 256, 0, stream>>>(w_ih, w_hh, Wt, Ut);
    tgn_scatter<<<NEV / 4, 256, 0, stream>>>(memory, raw_msg, time_w, time_b,
                                             last_update, src, dst, tarr,
                                             counts, S2, S3, S4);
    tgn_gru<<<NND / NB, 512, 0, stream>>>(memory, Wt, Ut, b_ih, b_hh,
                                          counts, S2, S3, S4, out);
}

// Round 3
// 672.895 us; speedup vs baseline: 6.6248x; 1.3543x over previous
//
#include <hip/hip_runtime.h>
#include <math.h>

#define NND 200000
#define NEV 100000
#define MD 100
#define TD 100
#define MSGD 172
#define NB 64

typedef __attribute__((ext_vector_type(8))) short bf16x8;
typedef __attribute__((ext_vector_type(4))) float f32x4;

__device__ __forceinline__ float sigmoidf_(float x) { return 1.0f / (1.0f + expf(-x)); }

__device__ __forceinline__ unsigned short f2bf(float f) {
    union { float f; unsigned int u; } v; v.f = f;
    unsigned int r = (v.u + 0x7FFFu + ((v.u >> 16) & 1u)) >> 16;
    return (unsigned short)r;
}
__device__ __forceinline__ float bf2f(unsigned short h) {
    union { unsigned int u; float f; } v; v.u = ((unsigned int)h) << 16;
    return v.f;
}

// ---------------- scatter: per-event message accumulation (unchanged) ----------------
__global__ __launch_bounds__(256) void tgn_scatter(
    const float* __restrict__ memory, const float* __restrict__ raw_msg,
    const float* __restrict__ time_w, const float* __restrict__ time_b,
    const int* __restrict__ last_update, const int* __restrict__ src,
    const int* __restrict__ dst, const int* __restrict__ tarr,
    float* __restrict__ counts, float* __restrict__ S2,
    float* __restrict__ S3, float* __restrict__ S4)
{
    int e = blockIdx.x * 4 + (threadIdx.x >> 6);
    if (e >= NEV) return;
    int lane = threadIdx.x & 63;
    int s = src[e], d = dst[e];
    int tt = tarr[e];
    float trs = (float)(tt - last_update[s]);
    float trd = (float)(tt - last_update[d]);

    for (int k = lane; k < MSGD; k += 64) {
        float r = raw_msg[e * MSGD + k];
        unsafeAtomicAdd(&S3[(size_t)s * MSGD + k], r);
        unsafeAtomicAdd(&S3[(size_t)d * MSGD + k], r);
    }
    for (int k = lane; k < MD; k += 64) {
        float ms = memory[(size_t)s * MD + k];
        float md = memory[(size_t)d * MD + k];
        unsafeAtomicAdd(&S2[(size_t)s * MD + k], md);
        unsafeAtomicAdd(&S2[(size_t)d * MD + k], ms);
        float tw = time_w[k];
        float tb = time_b[k];
        unsafeAtomicAdd(&S4[(size_t)s * TD + k], cosf(trs * tw + tb));
        unsafeAtomicAdd(&S4[(size_t)d * TD + k], cosf(trd * tw + tb));
    }
    if (lane == 0) {
        unsafeAtomicAdd(&counts[s], 1.0f);
        unsafeAtomicAdd(&counts[d], 1.0f);
    }
}

// ---------------- weight prep: bf16 in MFMA B-fragment order ----------------
// Wp[ks 15][nw 4][f 5][lane 64][e 8]; col = nw*80+f*16+(lane&15); k = ks*32+((lane>>4)<<3)+e
// Up[ks 4][nw 4][f 5][lane 64][e 8]; same col; k over [0,128) padded
#define WP_SH (15 * 4 * 5 * 64 * 8)
#define UP_SH (4 * 4 * 5 * 64 * 8)
__global__ __launch_bounds__(256) void tgn_prep(
    const float* __restrict__ w_ih, const float* __restrict__ w_hh,
    unsigned short* __restrict__ Wp, unsigned short* __restrict__ Up)
{
    int idx = blockIdx.x * 256 + threadIdx.x;
    if (idx < WP_SH) {
        int e = idx & 7;
        int lane = (idx >> 3) & 63;
        int t = idx >> 9;          // frag index: ((ks*4+nw)*5+f)
        int f = t % 5;
        int t2 = t / 5;
        int nw = t2 & 3;
        int ks = t2 >> 2;
        int col = nw * 80 + f * 16 + (lane & 15);
        int k = ks * 32 + ((lane >> 4) << 3) + e;
        float v = (col < 300 && k < 472) ? w_ih[col * 472 + k] : 0.0f;
        Wp[idx] = f2bf(v);
    } else {
        int j = idx - WP_SH;
        if (j < UP_SH) {
            int e = j & 7;
            int lane = (j >> 3) & 63;
            int t = j >> 9;
            int f = t % 5;
            int t2 = t / 5;
            int nw = t2 & 3;
            int ks = t2 >> 2;
            int col = nw * 80 + f * 16 + (lane & 15);
            int k = ks * 32 + ((lane >> 4) << 3) + e;
            float v = (col < 300 && k < 100) ? w_hh[col * 100 + k] : 0.0f;
            Up[j] = f2bf(v);
        }
    }
}

// ---------------- GRU via bf16 MFMA over 64-node tiles ----------------
// LDS ag: bf16 [64 nodes][480 k], XOR-swizzled: byte ^= (row&7)<<4
__global__ __launch_bounds__(512) void tgn_gru(
    const float* __restrict__ memory,
    const unsigned short* __restrict__ Wp, const unsigned short* __restrict__ Up,
    const float* __restrict__ b_ih, const float* __restrict__ b_hh,
    const float* __restrict__ counts, const float* __restrict__ S2,
    const float* __restrict__ S3, const float* __restrict__ S4,
    float* __restrict__ out)
{
    __shared__ __align__(16) unsigned short lds[64 * 480];  // 61440 B, reused by epilogue
    __shared__ float cnt_s[NB], cinv_s[NB];
    int tid = threadIdx.x;
    int n0 = blockIdx.x * NB;

    if (tid < NB) {
        float c = counts[n0 + tid];
        cnt_s[tid] = c;
        cinv_s[tid] = 1.0f / fmaxf(c, 1.0f);
    }
    __syncthreads();

    auto stage4 = [&](int n, int k, float x, float y, float z, float w) {
        int byte = (n * 960 + 2 * k) ^ ((n & 7) << 4);
        ushort4 h;
        h.x = f2bf(x); h.y = f2bf(y); h.z = f2bf(z); h.w = f2bf(w);
        *reinterpret_cast<ushort4*>(reinterpret_cast<char*>(lds) + byte) = h;
    };

    // cols [0,100): memory
    for (int i = tid; i < 1600; i += 512) {
        int n = i / 25, q = i - n * 25;
        float4 v = reinterpret_cast<const float4*>(memory)[(size_t)(n0 + n) * 25 + q];
        stage4(n, 4 * q, v.x, v.y, v.z, v.w);
    }
    // cols [100,200): S2 / counts
    for (int i = tid; i < 1600; i += 512) {
        int n = i / 25, q = i - n * 25;
        float4 v = reinterpret_cast<const float4*>(S2)[(size_t)(n0 + n) * 25 + q];
        float ci = cinv_s[n];
        stage4(n, 100 + 4 * q, v.x * ci, v.y * ci, v.z * ci, v.w * ci);
    }
    // cols [200,372): S3 / counts
    for (int i = tid; i < 2752; i += 512) {
        int n = i / 43, q = i - n * 43;
        float4 v = reinterpret_cast<const float4*>(S3)[(size_t)(n0 + n) * 43 + q];
        float ci = cinv_s[n];
        stage4(n, 200 + 4 * q, v.x * ci, v.y * ci, v.z * ci, v.w * ci);
    }
    // cols [372,472): S4 / counts
    for (int i = tid; i < 1600; i += 512) {
        int n = i / 25, q = i - n * 25;
        float4 v = reinterpret_cast<const float4*>(S4)[(size_t)(n0 + n) * 25 + q];
        float ci = cinv_s[n];
        stage4(n, 372 + 4 * q, v.x * ci, v.y * ci, v.z * ci, v.w * ci);
    }
    // cols [472,480): zero pad
    for (int i = tid; i < 128; i += 512) {
        int n = i >> 1, q = i & 1;
        stage4(n, 472 + 4 * q, 0.0f, 0.0f, 0.0f, 0.0f);
    }
    __syncthreads();

    // wave layout: 2 M-groups x 4 N-groups; wave = 2 row-frags x 5 col-frags
    int lane = tid & 63;
    int wv = tid >> 6;
    int nw = wv & 3;   // N group: cols [nw*80, +80)
    int mw = wv >> 2;  // M group: rows [mw*32, +32)
    int l15 = lane & 15;
    int kg = (lane >> 4) << 3;  // 0,8,16,24

    f32x4 accA[2][5], accH[2][5];
#pragma unroll
    for (int g = 0; g < 2; ++g)
#pragma unroll
        for (int f = 0; f < 5; ++f) {
            accA[g][f] = (f32x4){0.f, 0.f, 0.f, 0.f};
            accH[g][f] = (f32x4){0.f, 0.f, 0.f, 0.f};
        }

    int arow0 = mw * 32 + l15;
    const bf16x8* WpB = reinterpret_cast<const bf16x8*>(Wp);
    const bf16x8* UpB = reinterpret_cast<const bf16x8*>(Up);

    // gi: K = 480 (15 steps)
    for (int ks = 0; ks < 15; ++ks) {
        int k0 = ks * 32;
        bf16x8 a0, a1;
        {
            int r0 = arow0, r1 = arow0 + 16;
            int ab0 = (r0 * 960 + 2 * (k0 + kg)) ^ ((r0 & 7) << 4);
            int ab1 = (r1 * 960 + 2 * (k0 + kg)) ^ ((r1 & 7) << 4);
            a0 = *reinterpret_cast<const bf16x8*>(reinterpret_cast<const char*>(lds) + ab0);
            a1 = *reinterpret_cast<const bf16x8*>(reinterpret_cast<const char*>(lds) + ab1);
        }
        const bf16x8* wp = WpB + ((size_t)(ks * 4 + nw) * 5) * 64 + lane;
#pragma unroll
        for (int f = 0; f < 5; ++f) {
            bf16x8 b = wp[f * 64];
            accA[0][f] = __builtin_amdgcn_mfma_f32_16x16x32_bf16(a0, b, accA[0][f], 0, 0, 0);
            accA[1][f] = __builtin_amdgcn_mfma_f32_16x16x32_bf16(a1, b, accA[1][f], 0, 0, 0);
        }
    }
    // gh: K = 128 (4 steps); ag cols 100..127 are garbage but Up is zero there
    for (int ks = 0; ks < 4; ++ks) {
        int k0 = ks * 32;
        bf16x8 a0, a1;
        {
            int r0 = arow0, r1 = arow0 + 16;
            int ab0 = (r0 * 960 + 2 * (k0 + kg)) ^ ((r0 & 7) << 4);
            int ab1 = (r1 * 960 + 2 * (k0 + kg)) ^ ((r1 & 7) << 4);
            a0 = *reinterpret_cast<const bf16x8*>(reinterpret_cast<const char*>(lds) + ab0);
            a1 = *reinterpret_cast<const bf16x8*>(reinterpret_cast<const char*>(lds) + ab1);
        }
        const bf16x8* up = UpB + ((size_t)(ks * 4 + nw) * 5) * 64 + lane;
#pragma unroll
        for (int f = 0; f < 5; ++f) {
            bf16x8 b = up[f * 64];
            accH[0][f] = __builtin_amdgcn_mfma_f32_16x16x32_bf16(a0, b, accH[0][f], 0, 0, 0);
            accH[1][f] = __builtin_amdgcn_mfma_f32_16x16x32_bf16(a1, b, accH[1][f], 0, 0, 0);
        }
    }

    __syncthreads();  // all waves done reading ag; reuse LDS for gate staging

    // LDS reuse: gsum bf16 [64][208] | gin bf16 [64][104] | ghn bf16 [64][104]
    unsigned short* gsum = lds;
    unsigned short* gin = lds + 64 * 208;
    unsigned short* ghn = gin + 64 * 104;

#pragma unroll
    for (int f = 0; f < 5; ++f) {
        int col = nw * 80 + f * 16 + l15;
        if (col < 300) {
            float bi = b_ih[col], bh = b_hh[col];
#pragma unroll
            for (int g = 0; g < 2; ++g) {
                int node0 = mw * 32 + g * 16 + ((lane >> 4) << 2);
#pragma unroll
                for (int r = 0; r < 4; ++r) {
                    int node = node0 + r;
                    float gi = accA[g][f][r] + bi;
                    float gh = accH[g][f][r] + bh;
                    if (col < 200) {
                        gsum[node * 208 + col] = f2bf(gi + gh);
                    } else {
                        gin[node * 104 + (col - 200)] = f2bf(gi);
                        ghn[node * 104 + (col - 200)] = f2bf(gh);
                    }
                }
            }
        }
    }
    __syncthreads();

    // recombine gates -> GRU output
    for (int idx = tid; idx < NB * MD; idx += 512) {
        int n = idx / MD, j = idx - n * MD;
        float rp = bf2f(gsum[n * 208 + j]);
        float zp = bf2f(gsum[n * 208 + 100 + j]);
        float inv = bf2f(gin[n * 104 + j]);
        float hnv = bf2f(ghn[n * 104 + j]);
        float r = sigmoidf_(rp);
        float z = sigmoidf_(zp);
        float nn = tanhf(inv + r * hnv);
        float mv = memory[(size_t)(n0 + n) * MD + j];
        float h = (1.0f - z) * nn + z * mv;
        out[(size_t)(n0 + n) * MD + j] = (cnt_s[n] > 0.0f) ? h : mv;
    }
}

extern "C" void kernel_launch(void* const* d_in, const int* in_sizes, int n_in,
                              void* d_out, int out_size, void* d_ws, size_t ws_size,
                              hipStream_t stream)
{
    const float* memory      = (const float*)d_in[0];
    const float* raw_msg     = (const float*)d_in[1];
    const float* time_w      = (const float*)d_in[2];
    const float* time_b      = (const float*)d_in[3];
    const float* w_ih        = (const float*)d_in[4];
    const float* w_hh        = (const float*)d_in[5];
    const float* b_ih        = (const float*)d_in[6];
    const float* b_hh        = (const float*)d_in[7];
    const int*   last_update = (const int*)d_in[8];
    const int*   src         = (const int*)d_in[9];
    const int*   dst         = (const int*)d_in[10];
    const int*   tarr        = (const int*)d_in[11];
    float* out = (float*)d_out;

    // ws layout (floats): counts[N] | S2[N*100] | S3[N*172] | S4[N*100] | Wp | Up
    size_t s_floats = (size_t)373 * NND;
    size_t need = s_floats * sizeof(float) + (WP_SH + UP_SH) * sizeof(unsigned short);
    if (ws_size < need) return;
    float* ws     = (float*)d_ws;
    float* counts = ws;
    float* S2     = ws + (size_t)NND;
    float* S3     = ws + (size_t)101 * NND;
    float* S4     = ws + (size_t)273 * NND;
    unsigned short* Wp = (unsigned short*)(ws + s_floats);
    unsigned short* Up = Wp + WP_SH;

    hipMemsetAsync(d_ws, 0, s_floats * sizeof(float), stream);
    tgn_prep<<<(WP_SH + UP_SH + 255) / 256, 256, 0, stream>>>(w_ih, w_hh, Wp, Up);
    tgn_scatter<<<NEV / 4, 256, 0, stream>>>(memory, raw_msg, time_w, time_b,
                                             last_update, src, dst, tarr,
                                             counts, S2, S3, S4);
    tgn_gru<<<NND / NB, 512, 0, stream>>>(memory, Wp, Up, b_ih, b_hh,
                                          counts, S2, S3, S4, out);
}

// Round 4
// 378.153 us; speedup vs baseline: 11.7884x; 1.7794x over previous
//
#include <hip/hip_runtime.h>
#include <math.h>

#define NND 200000
#define NEV 100000
#define MD 100
#define TD 100
#define MSGD 172
#define NB 64

typedef __attribute__((ext_vector_type(8))) short bf16x8;
typedef __attribute__((ext_vector_type(4))) float f32x4;

__device__ __forceinline__ float sigmoidf_(float x) { return 1.0f / (1.0f + expf(-x)); }

__device__ __forceinline__ unsigned short f2bf(float f) {
    union { float f; unsigned int u; } v; v.f = f;
    unsigned int r = (v.u + 0x7FFFu + ((v.u >> 16) & 1u)) >> 16;
    return (unsigned short)r;
}
__device__ __forceinline__ float bf2f(unsigned short h) {
    union { unsigned int u; float f; } v; v.u = ((unsigned int)h) << 16;
    return v.f;
}

// ---------------- K2: count events per node ----------------
__global__ __launch_bounds__(256) void k_count(
    const int* __restrict__ src, const int* __restrict__ dst, int* __restrict__ cnt)
{
    int e = blockIdx.x * 256 + threadIdx.x;
    if (e >= NEV) return;
    atomicAdd(&cnt[src[e]], 1);
    atomicAdd(&cnt[dst[e]], 1);
}

// ---------------- K3a: per-1024-block exclusive scan ----------------
__global__ __launch_bounds__(256) void k_scan1(
    const int* __restrict__ cnt, int* __restrict__ off, int* __restrict__ psum)
{
    __shared__ int sdat[256];
    int t = threadIdx.x, b = blockIdx.x;
    int i0 = b * 1024 + t * 4;
    int v0 = (i0 + 0 < NND) ? cnt[i0 + 0] : 0;
    int v1 = (i0 + 1 < NND) ? cnt[i0 + 1] : 0;
    int v2 = (i0 + 2 < NND) ? cnt[i0 + 2] : 0;
    int v3 = (i0 + 3 < NND) ? cnt[i0 + 3] : 0;
    int tsum = v0 + v1 + v2 + v3;
    sdat[t] = tsum;
    __syncthreads();
    for (int o = 1; o < 256; o <<= 1) {
        int x = (t >= o) ? sdat[t - o] : 0;
        __syncthreads();
        sdat[t] += x;
        __syncthreads();
    }
    int excl = sdat[t] - tsum;
    if (i0 + 0 < NND) off[i0 + 0] = excl;
    if (i0 + 1 < NND) off[i0 + 1] = excl + v0;
    if (i0 + 2 < NND) off[i0 + 2] = excl + v0 + v1;
    if (i0 + 3 < NND) off[i0 + 3] = excl + v0 + v1 + v2;
    if (t == 255) psum[b] = sdat[255];
}

// ---------------- K3b: scan the 196 block sums ----------------
__global__ __launch_bounds__(256) void k_scan2(int* __restrict__ psum, int nblk)
{
    __shared__ int sdat[256];
    int t = threadIdx.x;
    int v = (t < nblk) ? psum[t] : 0;
    sdat[t] = v;
    __syncthreads();
    for (int o = 1; o < 256; o <<= 1) {
        int x = (t >= o) ? sdat[t - o] : 0;
        __syncthreads();
        sdat[t] += x;
        __syncthreads();
    }
    if (t < nblk) psum[t] = sdat[t] - v;  // exclusive
}

// ---------------- K3c: add block offsets; init cursor ----------------
__global__ __launch_bounds__(256) void k_scan3(
    int* __restrict__ off, const int* __restrict__ psum, int* __restrict__ cur)
{
    int t = threadIdx.x, b = blockIdx.x;
    int base = psum[b];
    int i0 = b * 1024 + t * 4;
#pragma unroll
    for (int j = 0; j < 4; ++j) {
        int i = i0 + j;
        if (i < NND) {
            int v = off[i] + base;
            off[i] = v;
            cur[i] = v;
        }
    }
}

// ---------------- K4: place entries (other, eid, trel) ----------------
__global__ __launch_bounds__(256) void k_place(
    const int* __restrict__ src, const int* __restrict__ dst,
    const int* __restrict__ tarr, const int* __restrict__ last_update,
    int* __restrict__ cur, int4* __restrict__ entries)
{
    int e = blockIdx.x * 256 + threadIdx.x;
    if (e >= NEV) return;
    int s = src[e], d = dst[e], tt = tarr[e];
    int slot = atomicAdd(&cur[s], 1);
    entries[slot] = make_int4(d, e, __float_as_int((float)(tt - last_update[s])), 0);
    slot = atomicAdd(&cur[d], 1);
    entries[slot] = make_int4(s, e, __float_as_int((float)(tt - last_update[d])), 0);
}

// ---------------- K5: time-encoding table per slot ----------------
__global__ __launch_bounds__(256) void k_tenc(
    const int4* __restrict__ entries, const float* __restrict__ time_w,
    const float* __restrict__ time_b, unsigned short* __restrict__ tenc)
{
    int slot = blockIdx.x * 2 + (threadIdx.x >> 7);
    int k = threadIdx.x & 127;
    if (k >= TD) return;
    float trel = __int_as_float(entries[slot].z);
    float v = cosf(trel * time_w[k] + time_b[k]);
    tenc[(size_t)slot * TD + k] = f2bf(v);
}

// ---------------- weight prep: bf16 in MFMA B-fragment order ----------------
#define WP_SH (15 * 4 * 5 * 64 * 8)
#define UP_SH (4 * 4 * 5 * 64 * 8)
__global__ __launch_bounds__(256) void tgn_prep(
    const float* __restrict__ w_ih, const float* __restrict__ w_hh,
    unsigned short* __restrict__ Wp, unsigned short* __restrict__ Up)
{
    int idx = blockIdx.x * 256 + threadIdx.x;
    if (idx < WP_SH) {
        int e = idx & 7;
        int lane = (idx >> 3) & 63;
        int t = idx >> 9;
        int f = t % 5;
        int t2 = t / 5;
        int nw = t2 & 3;
        int ks = t2 >> 2;
        int col = nw * 80 + f * 16 + (lane & 15);
        int k = ks * 32 + ((lane >> 4) << 3) + e;
        float v = (col < 300 && k < 472) ? w_ih[col * 472 + k] : 0.0f;
        Wp[idx] = f2bf(v);
    } else {
        int j = idx - WP_SH;
        if (j < UP_SH) {
            int e = j & 7;
            int lane = (j >> 3) & 63;
            int t = j >> 9;
            int f = t % 5;
            int t2 = t / 5;
            int nw = t2 & 3;
            int ks = t2 >> 2;
            int col = nw * 80 + f * 16 + (lane & 15);
            int k = ks * 32 + ((lane >> 4) << 3) + e;
            float v = (col < 300 && k < 100) ? w_hh[col * 100 + k] : 0.0f;
            Up[j] = f2bf(v);
        }
    }
}

// ---------------- GRU: gather staging + bf16 MFMA ----------------
__global__ __launch_bounds__(512) void tgn_gru(
    const float* __restrict__ memory, const float* __restrict__ raw_msg,
    const unsigned short* __restrict__ Wp, const unsigned short* __restrict__ Up,
    const float* __restrict__ b_ih, const float* __restrict__ b_hh,
    const int* __restrict__ cnt, const int* __restrict__ off,
    const int4* __restrict__ entries, const unsigned short* __restrict__ tenc,
    float* __restrict__ out)
{
    __shared__ __align__(16) unsigned short lds[64 * 480];
    __shared__ float cnt_s[NB];
    int tid = threadIdx.x;
    int n0 = blockIdx.x * NB;

    if (tid < NB) cnt_s[tid] = (float)cnt[n0 + tid];
    __syncthreads();

    auto stage4 = [&](int n, int k, float x, float y, float z, float w) {
        int byte = (n * 960 + 2 * k) ^ ((n & 7) << 4);
        ushort4 h;
        h.x = f2bf(x); h.y = f2bf(y); h.z = f2bf(z); h.w = f2bf(w);
        *reinterpret_cast<ushort4*>(reinterpret_cast<char*>(lds) + byte) = h;
    };

    // cols [0,100): memory (mem_self aggregate == memory[n])
    for (int i = tid; i < 1600; i += 512) {
        int n = i / 25, q = i - n * 25;
        float4 v = reinterpret_cast<const float4*>(memory)[(size_t)(n0 + n) * 25 + q];
        stage4(n, 4 * q, v.x, v.y, v.z, v.w);
    }
    // cols [472,480): zero pad
    for (int i = tid; i < 128; i += 512) {
        int n = i >> 1, q = i & 1;
        stage4(n, 472 + 4 * q, 0.0f, 0.0f, 0.0f, 0.0f);
    }

    // cols [100,472): per-node event gather; 8 threads per node
    {
        int nl = tid >> 3;          // local node 0..63
        int tsub = tid & 7;
        int node = n0 + nl;
        int c = cnt[node];
        int o0 = off[node];
        float4 acc[12];
#pragma unroll
        for (int j = 0; j < 12; ++j) acc[j] = (float4){0.f, 0.f, 0.f, 0.f};

        for (int i = 0; i < c; ++i) {
            int4 en = entries[o0 + i];
            const float4* mo = reinterpret_cast<const float4*>(memory + (size_t)en.x * MD);
            const float4* rw = reinterpret_cast<const float4*>(raw_msg + (size_t)en.y * MSGD);
            const ushort4* te = reinterpret_cast<const ushort4*>(tenc + (size_t)(o0 + i) * TD);
#pragma unroll
            for (int j = 0; j < 12; ++j) {
                int q = tsub + 8 * j;
                if (q < 93) {
                    float4 v;
                    if (q < 25) {
                        v = mo[q];
                    } else if (q < 68) {
                        v = rw[q - 25];
                    } else {
                        ushort4 h = te[q - 68];
                        v = (float4){bf2f(h.x), bf2f(h.y), bf2f(h.z), bf2f(h.w)};
                    }
                    acc[j].x += v.x; acc[j].y += v.y; acc[j].z += v.z; acc[j].w += v.w;
                }
            }
        }
        float ci = 1.0f / fmaxf((float)c, 1.0f);
#pragma unroll
        for (int j = 0; j < 12; ++j) {
            int q = tsub + 8 * j;
            if (q < 93)
                stage4(nl, 100 + 4 * q, acc[j].x * ci, acc[j].y * ci, acc[j].z * ci, acc[j].w * ci);
        }
    }
    __syncthreads();

    // wave layout: 2 M-groups x 4 N-groups; wave = 2 row-frags x 5 col-frags
    int lane = tid & 63;
    int wv = tid >> 6;
    int nw = wv & 3;
    int mw = wv >> 2;
    int l15 = lane & 15;
    int kg = (lane >> 4) << 3;

    f32x4 accA[2][5], accH[2][5];
#pragma unroll
    for (int g = 0; g < 2; ++g)
#pragma unroll
        for (int f = 0; f < 5; ++f) {
            accA[g][f] = (f32x4){0.f, 0.f, 0.f, 0.f};
            accH[g][f] = (f32x4){0.f, 0.f, 0.f, 0.f};
        }

    int arow0 = mw * 32 + l15;
    const bf16x8* WpB = reinterpret_cast<const bf16x8*>(Wp);
    const bf16x8* UpB = reinterpret_cast<const bf16x8*>(Up);

    for (int ks = 0; ks < 15; ++ks) {
        int k0 = ks * 32;
        bf16x8 a0, a1;
        {
            int r0 = arow0, r1 = arow0 + 16;
            int ab0 = (r0 * 960 + 2 * (k0 + kg)) ^ ((r0 & 7) << 4);
            int ab1 = (r1 * 960 + 2 * (k0 + kg)) ^ ((r1 & 7) << 4);
            a0 = *reinterpret_cast<const bf16x8*>(reinterpret_cast<const char*>(lds) + ab0);
            a1 = *reinterpret_cast<const bf16x8*>(reinterpret_cast<const char*>(lds) + ab1);
        }
        const bf16x8* wp = WpB + ((size_t)(ks * 4 + nw) * 5) * 64 + lane;
#pragma unroll
        for (int f = 0; f < 5; ++f) {
            bf16x8 b = wp[f * 64];
            accA[0][f] = __builtin_amdgcn_mfma_f32_16x16x32_bf16(a0, b, accA[0][f], 0, 0, 0);
            accA[1][f] = __builtin_amdgcn_mfma_f32_16x16x32_bf16(a1, b, accA[1][f], 0, 0, 0);
        }
    }
    for (int ks = 0; ks < 4; ++ks) {
        int k0 = ks * 32;
        bf16x8 a0, a1;
        {
            int r0 = arow0, r1 = arow0 + 16;
            int ab0 = (r0 * 960 + 2 * (k0 + kg)) ^ ((r0 & 7) << 4);
            int ab1 = (r1 * 960 + 2 * (k0 + kg)) ^ ((r1 & 7) << 4);
            a0 = *reinterpret_cast<const bf16x8*>(reinterpret_cast<const char*>(lds) + ab0);
            a1 = *reinterpret_cast<const bf16x8*>(reinterpret_cast<const char*>(lds) + ab1);
        }
        const bf16x8* up = UpB + ((size_t)(ks * 4 + nw) * 5) * 64 + lane;
#pragma unroll
        for (int f = 0; f < 5; ++f) {
            bf16x8 b = up[f * 64];
            accH[0][f] = __builtin_amdgcn_mfma_f32_16x16x32_bf16(a0, b, accH[0][f], 0, 0, 0);
            accH[1][f] = __builtin_amdgcn_mfma_f32_16x16x32_bf16(a1, b, accH[1][f], 0, 0, 0);
        }
    }

    __syncthreads();  // reuse LDS for gate staging

    unsigned short* gsum = lds;
    unsigned short* gin = lds + 64 * 208;
    unsigned short* ghn = gin + 64 * 104;

#pragma unroll
    for (int f = 0; f < 5; ++f) {
        int col = nw * 80 + f * 16 + l15;
        if (col < 300) {
            float bi = b_ih[col], bh = b_hh[col];
#pragma unroll
            for (int g = 0; g < 2; ++g) {
                int node0 = mw * 32 + g * 16 + ((lane >> 4) << 2);
#pragma unroll
                for (int r = 0; r < 4; ++r) {
                    int node = node0 + r;
                    float gi = accA[g][f][r] + bi;
                    float gh = accH[g][f][r] + bh;
                    if (col < 200) {
                        gsum[node * 208 + col] = f2bf(gi + gh);
                    } else {
                        gin[node * 104 + (col - 200)] = f2bf(gi);
                        ghn[node * 104 + (col - 200)] = f2bf(gh);
                    }
                }
            }
        }
    }
    __syncthreads();

    for (int idx = tid; idx < NB * MD; idx += 512) {
        int n = idx / MD, j = idx - n * MD;
        float rp = bf2f(gsum[n * 208 + j]);
        float zp = bf2f(gsum[n * 208 + 100 + j]);
        float inv = bf2f(gin[n * 104 + j]);
        float hnv = bf2f(ghn[n * 104 + j]);
        float r = sigmoidf_(rp);
        float z = sigmoidf_(zp);
        float nn = tanhf(inv + r * hnv);
        float mv = memory[(size_t)(n0 + n) * MD + j];
        float h = (1.0f - z) * nn + z * mv;
        out[(size_t)(n0 + n) * MD + j] = (cnt_s[n] > 0.0f) ? h : mv;
    }
}

extern "C" void kernel_launch(void* const* d_in, const int* in_sizes, int n_in,
                              void* d_out, int out_size, void* d_ws, size_t ws_size,
                              hipStream_t stream)
{
    const float* memory      = (const float*)d_in[0];
    const float* raw_msg     = (const float*)d_in[1];
    const float* time_w      = (const float*)d_in[2];
    const float* time_b      = (const float*)d_in[3];
    const float* w_ih        = (const float*)d_in[4];
    const float* w_hh        = (const float*)d_in[5];
    const float* b_ih        = (const float*)d_in[6];
    const float* b_hh        = (const float*)d_in[7];
    const int*   last_update = (const int*)d_in[8];
    const int*   src         = (const int*)d_in[9];
    const int*   dst         = (const int*)d_in[10];
    const int*   tarr        = (const int*)d_in[11];
    float* out = (float*)d_out;

    // ws layout: cnt[N] off[N] cur[N] psum[256] | entries int4[2E] | tenc u16[2E*100] | Wp | Up
    int* cnt  = (int*)d_ws;
    int* off  = cnt + NND;
    int* cur  = off + NND;
    int* psum = cur + NND;
    int4* entries = (int4*)(psum + 256);
    unsigned short* tenc = (unsigned short*)(entries + 2 * NEV);
    unsigned short* Wp = tenc + (size_t)2 * NEV * TD;
    unsigned short* Up = Wp + WP_SH;
    size_t need = (size_t)((char*)(Up + UP_SH) - (char*)d_ws);
    if (ws_size < need) return;

    const int NBLK = (NND + 1023) / 1024;  // 196

    hipMemsetAsync(cnt, 0, NND * sizeof(int), stream);
    tgn_prep<<<(WP_SH + UP_SH + 255) / 256, 256, 0, stream>>>(w_ih, w_hh, Wp, Up);
    k_count<<<(NEV + 255) / 256, 256, 0, stream>>>(src, dst, cnt);
    k_scan1<<<NBLK, 256, 0, stream>>>(cnt, off, psum);
    k_scan2<<<1, 256, 0, stream>>>(psum, NBLK);
    k_scan3<<<NBLK, 256, 0, stream>>>(off, psum, cur);
    k_place<<<(NEV + 255) / 256, 256, 0, stream>>>(src, dst, tarr, last_update, cur, entries);
    k_tenc<<<NEV, 256, 0, stream>>>(entries, time_w, time_b, tenc);
    tgn_gru<<<NND / NB, 512, 0, stream>>>(memory, raw_msg, Wp, Up, b_ih, b_hh,
                                          cnt, off, entries, tenc, out);
}